// Round 21
// baseline (72.771 us; speedup 1.0000x reference)
//
#include <hip/hip_runtime.h>
#include <hip/hip_bf16.h>

typedef __attribute__((ext_vector_type(8))) short short8;
typedef __attribute__((ext_vector_type(4))) float f32x4;
typedef __attribute__((ext_vector_type(2))) float f32x2;

#define T_STEPS 32
#define H 128
#define FOURH 512
#define GSTRIDE 132       // shorts per gate section (128 + 4 pad)
#define SPITCH  528       // 4 * GSTRIDE shorts per bl row (1056 B)
#define E_DIM 64
#define TILE_B 32

#define NEG_LOG2E  -1.4426950408889634f
#define NEG_2LOG2E -2.8853900817779268f
#define CONV_TOL   0.04f

__device__ inline unsigned short f2bf(float x){
  unsigned int u = __builtin_bit_cast(unsigned int, x);
  unsigned int r = (u + 0x7FFFu + ((u >> 16) & 1u)) >> 16;
  return (unsigned short)r;
}

// 4 reciprocals for the price of 1 rcp (all d_k >= 1 here, no overflow risk)
__device__ inline void rcp4(float d0, float d1, float d2, float d3,
                            float& i0, float& i1, float& i2, float& i3){
  float p01 = d0 * d1, p23 = d2 * d3;
  float r = __builtin_amdgcn_rcpf(p01 * p23);
  float r01 = r * p23, r23 = r * p01;
  i0 = r01 * d1; i1 = r01 * d0;
  i2 = r23 * d3; i3 = r23 * d2;
}

template<int CTRL>
__device__ inline float dpp_ror_add(float x){
  int t = __builtin_amdgcn_update_dpp(0, __builtin_bit_cast(int, x), CTRL, 0xF, 0xF, true);
  return x + __builtin_bit_cast(float, t);
}
// Sum over each 16-lane DPP row (all 16 lanes receive the row sum).
// row_ror operates within 16-lane rows natively — no cross-row op needed.
__device__ inline float red16(float x){
  x = dpp_ror_add<0x121>(x);   // row_ror:1
  x = dpp_ror_add<0x122>(x);   // row_ror:2
  x = dpp_ror_add<0x124>(x);   // row_ror:4
  x = dpp_ror_add<0x128>(x);   // row_ror:8
  return x;
}

// ---- K1: blocks 0..255: W_hh f32 -> bf16 in MFMA-fragment-shuffled layout;
//          blocks 256..257: params. (layout verified R12)
__global__ void k_prep(const float* __restrict__ W_hh, unsigned short* __restrict__ Wb,
                       const float* __restrict__ W_ih, const float* __restrict__ b_ih,
                       const float* __restrict__ b_hh, const float* __restrict__ W_emb,
                       const float* __restrict__ b_emb, float* __restrict__ params){
  int bid = blockIdx.x;
  if (bid < 256){
    int f = bid * 256 + threadIdx.x;           // 65536 = FOURH*H exactly
    int i  = f & 7;
    int l  = (f >> 3) & 63;
    int c2 = (f >> 9) & 31;
    int kf = f >> 14;
    int col = c2 * 16 + (l & 15);
    int k   = kf * 32 + (l >> 4) * 8 + i;
    Wb[f] = f2bf(W_hh[col * H + k]);
    return;
  }
  int j = (bid - 256) * 256 + threadIdx.x;
  if (j >= FOURH) return;
  float su = 0.f, sv = 0.f, sm = 0.f, sb = 0.f;
  for (int e = 0; e < E_DIM; e++){
    float w = W_ih[j * E_DIM + e];
    su = fmaf(w, W_emb[e * 3 + 0], su);
    sv = fmaf(w, W_emb[e * 3 + 1], sv);
    sm = fmaf(w, W_emb[e * 3 + 2], sm);
    sb = fmaf(w, b_emb[e], sb);
  }
  float sc = ((j >> 7) == 2) ? NEG_2LOG2E : NEG_LOG2E;   // gate g uses tanh scale
  params[j] = su * sc;
  params[FOURH + j] = sv * sc;
  params[2 * FOURH + j] = sm;
  params[3 * FOURH + j] = sb + b_ih[j] + b_hh[j];
}

// ---- K2: fused base-GEMM (MFMA -> LDS, phase2-native layout) + recurrence.
// Phase 2: 16 lanes per b (8 dims/lane, d = li + 16k) -> 4 b's advance per
// chain-step in one instruction stream; 2 sequential passes cover 32 b's.
__global__ __launch_bounds__(256, 2) void k_fused(
    const float* __restrict__ h0, const unsigned short* __restrict__ W_bf,
    const float* __restrict__ spd, const float* __restrict__ params,
    const float* __restrict__ c0, const float* __restrict__ lpr,
    const float* __restrict__ W_pos, const float* __restrict__ b_pos,
    float* __restrict__ out, long B)
{
  __shared__ unsigned short sbase[TILE_B][SPITCH];  // 33 KB
  int tid = threadIdx.x;
  int l = tid & 63, w = tid >> 6;
  int row16 = l & 15, half = l >> 4;
  long m0 = (long)blockIdx.x * TILE_B;
  float* out2 = out + (size_t)T_STEPS * B * 2;  // h0 passthrough output

  // ---------- phase 1: base'[32][512] = sc*(h0@W_hh^T + bc + spd*m2) ----------
  short8 afrag[2][4];
  #pragma unroll
  for (int mf = 0; mf < 2; mf++){
    #pragma unroll
    for (int kf = 0; kf < 4; kf++){
      long row = m0 + mf * 16 + row16;
      const f32x4* p = (const f32x4*)(h0 + row * H + kf * 32 + half * 8);
      f32x4 x = p[0], y = p[1];
      if (kf == w){                              // h0 copy, distributed over waves
        f32x4* q = (f32x4*)(out2 + row * H + kf * 32 + half * 8);
        q[0] = x; q[1] = y;
      }
      short8 a;
      #pragma unroll
      for (int i = 0; i < 4; i++){ a[i] = (short)f2bf(x[i]); a[4 + i] = (short)f2bf(y[i]); }
      afrag[mf][kf] = a;
    }
  }
  f32x4 acc[2][8];
  #pragma unroll
  for (int mf = 0; mf < 2; mf++)
    #pragma unroll
    for (int n = 0; n < 8; n++) acc[mf][n] = (f32x4){0.f, 0.f, 0.f, 0.f};

  // double-buffered W loads from the SHUFFLED layout (contiguous 1KB/wave/instr)
  short8 bfr[2][8];
  #pragma unroll
  for (int nfi = 0; nfi < 8; nfi++)
    bfr[0][nfi] = *(const short8*)(W_bf + (size_t)(((0 * 32 + w * 8 + nfi) * 64 + l)) * 8);
  #pragma unroll
  for (int kf = 0; kf < 4; kf++){
    if (kf < 3){
      #pragma unroll
      for (int nfi = 0; nfi < 8; nfi++)
        bfr[(kf + 1) & 1][nfi] =
          *(const short8*)(W_bf + (size_t)((((kf + 1) * 32 + w * 8 + nfi) * 64 + l)) * 8);
    }
    #pragma unroll
    for (int nfi = 0; nfi < 8; nfi++){
      acc[0][nfi] = __builtin_amdgcn_mfma_f32_16x16x32_bf16(afrag[0][kf], bfr[kf & 1][nfi], acc[0][nfi], 0, 0, 0);
      acc[1][nfi] = __builtin_amdgcn_mfma_f32_16x16x32_bf16(afrag[1][kf], bfr[kf & 1][nfi], acc[1][nfi], 0, 0, 0);
    }
  }
  // Epilogue: write into phase2-native layout (verified R20).
  #pragma unroll
  for (int nfi = 0; nfi < 8; nfi++){
    int qq = w * 8 + nfi;
    int j = qq * 16 + row16;
    float bc = params[3 * FOURH + j];
    float m2 = params[2 * FOURH + j];
    float sc = ((qq >> 3) == 2) ? NEG_2LOG2E : NEG_LOG2E;
    int pos = (qq >> 3) * GSTRIDE + (((qq & 1) * 16 + row16) << 2) + ((qq >> 1) & 3);
    #pragma unroll
    for (int mf = 0; mf < 2; mf++){
      #pragma unroll
      for (int r = 0; r < 4; r++){
        int bl = mf * 16 + half * 4 + r;
        float v = sc * (acc[mf][nfi][r] + bc + spd[m0 + bl] * m2);
        sbase[bl][pos] = f2bf(v);
      }
    }
  }

  // ---- T14 issue-early: c0/lpr for BOTH passes issued before the barrier.
  int li = l & 15;
  int g4 = l >> 4;
  long bA = m0 + w * 8 + g4;        // pass 0 b
  long bBv = m0 + w * 8 + 4 + g4;   // pass 1 b
  float CDa[8], CDb[8]; f32x2 RPa, RPb;
  #pragma unroll
  for (int k = 0; k < 8; k++){
    CDa[k] = c0[bA * H + li + 16 * k];
    CDb[k] = c0[bBv * H + li + 16 * k];
  }
  RPa = ((const f32x2*)lpr)[bA];
  RPb = ((const f32x2*)lpr)[bBv];
  __syncthreads();

  // ---------- phase 2 ----------
  float uu[4][8], vv[4][8], wp0[8], wp1[8];
  #pragma unroll
  for (int k = 0; k < 8; k++){
    int d = li + 16 * k;
    #pragma unroll
    for (int g = 0; g < 4; g++){
      uu[g][k] = params[g * H + d];
      vv[g][k] = params[FOURH + g * H + d];
    }
    wp0[k] = W_pos[d];
    wp1[k] = W_pos[H + d];
  }
  float bp0 = b_pos[0], bp1 = b_pos[1];
  unsigned long long gmask16 = 0xFFFFull;
  int gsh = g4 << 4;

#define RUN_PASS(bcur, CDv, RPv)                                                \
  {                                                                             \
    int bl = (int)(bcur - m0);                                                  \
    float BB[4][8];                                                             \
    _Pragma("unroll")                                                           \
    for (int g = 0; g < 4; g++){                                                \
      unsigned long long qA = *(const unsigned long long*)&sbase[bl][g * GSTRIDE + (li << 2)];          \
      unsigned long long qB = *(const unsigned long long*)&sbase[bl][g * GSTRIDE + ((li + 16) << 2)];   \
      unsigned int a0_ = (unsigned int)qA, a1_ = (unsigned int)(qA >> 32);      \
      unsigned int b0_ = (unsigned int)qB, b1_ = (unsigned int)(qB >> 32);      \
      BB[g][0] = __builtin_bit_cast(float, a0_ << 16);                          \
      BB[g][2] = __builtin_bit_cast(float, a0_ & 0xFFFF0000u);                  \
      BB[g][4] = __builtin_bit_cast(float, a1_ << 16);                          \
      BB[g][6] = __builtin_bit_cast(float, a1_ & 0xFFFF0000u);                  \
      BB[g][1] = __builtin_bit_cast(float, b0_ << 16);                          \
      BB[g][3] = __builtin_bit_cast(float, b0_ & 0xFFFF0000u);                  \
      BB[g][5] = __builtin_bit_cast(float, b1_ << 16);                          \
      BB[g][7] = __builtin_bit_cast(float, b1_ & 0xFFFF0000u);                  \
    }                                                                           \
    float r0 = RPv[0], r1 = RPv[1];                                             \
    float sa0 = 0.f, sa1 = 0.f, sb0 = 0.f, sb1 = 0.f;                           \
    float pdx = 0.f, pdy = 0.f;                                                 \
    int done = 0, TL = T_STEPS - 1;                                             \
    for (int t = 0; t < T_STEPS; t++){                                          \
      float cn[8], so_[8];                                                      \
      _Pragma("unroll")                                                         \
      for (int k = 0; k < 8; k++){                                              \
        float gi = fmaf(r1, vv[0][k], fmaf(r0, uu[0][k], BB[0][k]));            \
        float gf = fmaf(r1, vv[1][k], fmaf(r0, uu[1][k], BB[1][k]));            \
        float gg = fmaf(r1, vv[2][k], fmaf(r0, uu[2][k], BB[2][k]));            \
        float go = fmaf(r1, vv[3][k], fmaf(r0, uu[3][k], BB[3][k]));            \
        float Di = 1.0f + __builtin_amdgcn_exp2f(gi);                           \
        float Df = 1.0f + __builtin_amdgcn_exp2f(gf);                           \
        float Dg = 1.0f + __builtin_amdgcn_exp2f(gg);                           \
        float Do = 1.0f + __builtin_amdgcn_exp2f(go);                           \
        float si, sf, ig, so;                                                   \
        rcp4(Di, Df, Dg, Do, si, sf, ig, so);                                   \
        float tg = fmaf(2.0f, ig, -1.0f);                                       \
        cn[k] = fmaf(sf, CDv[k], si * tg);                                      \
        so_[k] = so;                                                            \
      }                                                                         \
      float ic[8];                                                              \
      _Pragma("unroll")                                                         \
      for (int kq = 0; kq < 2; kq++){                                           \
        float D0 = 1.0f + __builtin_amdgcn_exp2f(NEG_2LOG2E * cn[kq*4+0]);      \
        float D1 = 1.0f + __builtin_amdgcn_exp2f(NEG_2LOG2E * cn[kq*4+1]);      \
        float D2 = 1.0f + __builtin_amdgcn_exp2f(NEG_2LOG2E * cn[kq*4+2]);      \
        float D3 = 1.0f + __builtin_amdgcn_exp2f(NEG_2LOG2E * cn[kq*4+3]);      \
        rcp4(D0, D1, D2, D3, ic[kq*4+0], ic[kq*4+1], ic[kq*4+2], ic[kq*4+3]);   \
      }                                                                         \
      float a0s = 0.f, a1s = 0.f;                                               \
      _Pragma("unroll")                                                         \
      for (int k = 0; k < 8; k++){                                              \
        float hv = so_[k] * fmaf(2.0f, ic[k], -1.0f);                           \
        a0s = fmaf(hv, wp0[k], a0s);                                            \
        a1s = fmaf(hv, wp1[k], a1s);                                            \
      }                                                                         \
      a0s = red16(a0s);                                                         \
      a1s = red16(a1s);                                                         \
      float n0 = a0s + bp0, n1 = a1s + bp1;                                     \
      float dx = n0 - r0, dy = n1 - r1;                                         \
      r0 = n0; r1 = n1;                                                         \
      sa0 = (li == t) ? n0 : sa0;  sa1 = (li == t) ? n1 : sa1;                  \
      sb0 = (li + 16 == t) ? n0 : sb0;  sb1 = (li + 16 == t) ? n1 : sb1;        \
      int cf = (__builtin_fabsf(dx) < CONV_TOL) & (__builtin_fabsf(dy) < CONV_TOL); \
      unsigned long long mb = __ballot(cf);                                     \
      int gd = (int)(((mb >> gsh) & gmask16) == gmask16);                       \
      /* scalar Aitken, group-uniform decision via ballot (R8 math) */          \
      float dcur2 = dx * dx + dy * dy;                                          \
      float dprev2 = pdx * pdx + pdy * pdy;                                     \
      float lam = (dx * pdx + dy * pdy) * __builtin_amdgcn_rcpf(dprev2);        \
      float rsx = dx - lam * pdx, rsy = dy - lam * pdy;                         \
      float res2 = rsx * rsx + rsy * rsy;                                       \
      float fA = lam * __builtin_amdgcn_rcpf(1.f - lam);                        \
      float esq = fA * fA * dcur2;                                              \
      int ok = (dprev2 > 1e-12f) & (res2 < 0.02f * dcur2) &                     \
               (__builtin_fabsf(lam) < 0.9f) &                                  \
               (esq < 2e-3f) & (dcur2 < 0.02f);                                 \
      unsigned long long mo = __ballot(ok);                                     \
      int gj = (t >= 1) & (int)(((mo >> gsh) & gmask16) == gmask16);            \
      float fj = ((!done) & (!gd) & gj) ? fA : 0.0f;                            \
      r0 = fmaf(fj, dx, r0);                                                    \
      r1 = fmaf(fj, dy, r1);                                                    \
      TL = ((!done) & (gd | gj)) ? t : TL;                                      \
      done = done | gd | gj;                                                    \
      pdx = dx; pdy = dy;                                                       \
      if (__all(done)) break;                                                   \
    }                                                                           \
    float o0a = (li > TL) ? r0 : sa0;                                           \
    float o1a = (li > TL) ? r1 : sa1;                                           \
    float o0b = (li + 16 > TL) ? r0 : sb0;                                      \
    float o1b = (li + 16 > TL) ? r1 : sb1;                                      \
    f32x2 oa; oa[0] = o0a; oa[1] = o1a;                                         \
    f32x2 ob; ob[0] = o0b; ob[1] = o1b;                                         \
    ((f32x2*)out)[(long)li * B + bcur] = oa;                                    \
    ((f32x2*)out)[(long)(li + 16) * B + bcur] = ob;                             \
  }

  RUN_PASS(bA, CDa, RPa)
  RUN_PASS(bBv, CDb, RPb)
#undef RUN_PASS
}

extern "C" void kernel_launch(void* const* d_in, const int* in_sizes, int n_in,
                              void* d_out, int out_size, void* d_ws, size_t ws_size,
                              hipStream_t stream) {
  const float* lpr   = (const float*)d_in[1];   // last_pos_rel [B,2]
  const float* h0    = (const float*)d_in[2];   // [1,B,H]
  const float* c0    = (const float*)d_in[3];   // [1,B,H]
  const float* spd   = (const float*)d_in[4];   // last_speed_pos_rel [B,1]
  const float* W_ih  = (const float*)d_in[7];
  const float* W_hh  = (const float*)d_in[8];
  const float* b_ih  = (const float*)d_in[9];
  const float* b_hh  = (const float*)d_in[10];
  const float* W_emb = (const float*)d_in[11];
  const float* b_emb = (const float*)d_in[12];
  const float* W_pos = (const float*)d_in[13];
  const float* b_pos = (const float*)d_in[14];
  long B = in_sizes[0] / 2;                     // 65536
  float* out = (float*)d_out;

  // ws layout: params (8KB) | W_hh bf16 shuffled (128KB)
  float* params = (float*)d_ws;
  size_t pbytes = (size_t)4 * FOURH * sizeof(float);
  unsigned short* wbf = (unsigned short*)((char*)d_ws + pbytes);

  hipLaunchKernelGGL(k_prep, dim3(258), dim3(256), 0, stream,
                     W_hh, wbf, W_ih, b_ih, b_hh, W_emb, b_emb, params);
  hipLaunchKernelGGL(k_fused, dim3(B / TILE_B), dim3(256), 0, stream,
                     h0, wbf, spd, params, c0, lpr, W_pos, b_pos, out, B);
}

// Round 22
// 62.775 us; speedup vs baseline: 1.1592x; 1.1592x over previous
//
#include <hip/hip_runtime.h>
#include <hip/hip_bf16.h>

typedef __attribute__((ext_vector_type(8))) short short8;
typedef __attribute__((ext_vector_type(4))) float f32x4;
typedef __attribute__((ext_vector_type(2))) float f32x2;

#define T_STEPS 32
#define H 128
#define FOURH 512
#define GSTRIDE 132       // shorts per gate section (128 + 4 pad)
#define SPITCH  528       // 4 * GSTRIDE shorts per bl row (1056 B)
#define E_DIM 64
#define TILE_B 32

#define NEG_LOG2E  -1.4426950408889634f
#define NEG_2LOG2E -2.8853900817779268f
#define CONV_TOL   0.04f

__device__ inline unsigned short f2bf(float x){
  unsigned int u = __builtin_bit_cast(unsigned int, x);
  unsigned int r = (u + 0x7FFFu + ((u >> 16) & 1u)) >> 16;
  return (unsigned short)r;
}

// 4 reciprocals for the price of 1 rcp (all d_k >= 1 here, no overflow risk)
__device__ inline void rcp4(float d0, float d1, float d2, float d3,
                            float& i0, float& i1, float& i2, float& i3){
  float p01 = d0 * d1, p23 = d2 * d3;
  float r = __builtin_amdgcn_rcpf(p01 * p23);
  float r01 = r * p23, r23 = r * p01;
  i0 = r01 * d1; i1 = r01 * d0;
  i2 = r23 * d3; i3 = r23 * d2;
}

template<int CTRL>
__device__ inline float dpp_ror_add(float x){
  int t = __builtin_amdgcn_update_dpp(0, __builtin_bit_cast(int, x), CTRL, 0xF, 0xF, true);
  return x + __builtin_bit_cast(float, t);
}
// Row-sum via 4 DPP stages, then add the partner row (l^32): with d = s = x,
// v_permlane32_swap_b32 exchanges one half of d with the opposite half of s —
// whichever direction HW uses, per lane exactly one of {d,s} holds x[l^32] and
// the other x[l], so d+s == x[l]+x[l^32] unconditionally (verified R6/R8).
__device__ inline float redb(float x){
  x = dpp_ror_add<0x121>(x);   // row_ror:1
  x = dpp_ror_add<0x122>(x);   // row_ror:2
  x = dpp_ror_add<0x124>(x);   // row_ror:4
  x = dpp_ror_add<0x128>(x);   // row_ror:8
  float d = x, s = x;
  asm("v_permlane32_swap_b32 %0, %1" : "+v"(d), "+v"(s));
  return d + s;
}

// ---- K1: blocks 0..255: W_hh f32 -> bf16 in MFMA-fragment-shuffled layout;
//          blocks 256..257: params. (layout verified R12)
__global__ void k_prep(const float* __restrict__ W_hh, unsigned short* __restrict__ Wb,
                       const float* __restrict__ W_ih, const float* __restrict__ b_ih,
                       const float* __restrict__ b_hh, const float* __restrict__ W_emb,
                       const float* __restrict__ b_emb, float* __restrict__ params){
  int bid = blockIdx.x;
  if (bid < 256){
    int f = bid * 256 + threadIdx.x;           // 65536 = FOURH*H exactly
    int i  = f & 7;
    int l  = (f >> 3) & 63;
    int c2 = (f >> 9) & 31;
    int kf = f >> 14;
    int col = c2 * 16 + (l & 15);
    int k   = kf * 32 + (l >> 4) * 8 + i;
    Wb[f] = f2bf(W_hh[col * H + k]);
    return;
  }
  int j = (bid - 256) * 256 + threadIdx.x;
  if (j >= FOURH) return;
  float su = 0.f, sv = 0.f, sm = 0.f, sb = 0.f;
  for (int e = 0; e < E_DIM; e++){
    float w = W_ih[j * E_DIM + e];
    su = fmaf(w, W_emb[e * 3 + 0], su);
    sv = fmaf(w, W_emb[e * 3 + 1], sv);
    sm = fmaf(w, W_emb[e * 3 + 2], sm);
    sb = fmaf(w, b_emb[e], sb);
  }
  float sc = ((j >> 7) == 2) ? NEG_2LOG2E : NEG_LOG2E;   // gate g uses tanh scale
  params[j] = su * sc;
  params[FOURH + j] = sv * sc;
  params[2 * FOURH + j] = sm;
  params[3 * FOURH + j] = sb + b_ih[j] + b_hh[j];
}

// ---- K2: fused base-GEMM (MFMA -> LDS, phase2-native layout) + recurrence.
// sbase layout: [bl][gate*GSTRIDE + li*4 + k] holds base'[d = li + 32k] so
// phase2 fetches each (gate, li) quadruple with ONE ds_read_b64.
__global__ __launch_bounds__(256, 2) void k_fused(
    const float* __restrict__ h0, const unsigned short* __restrict__ W_bf,
    const float* __restrict__ spd, const float* __restrict__ params,
    const float* __restrict__ c0, const float* __restrict__ lpr,
    const float* __restrict__ W_pos, const float* __restrict__ b_pos,
    float* __restrict__ out, long B)
{
  __shared__ unsigned short sbase[TILE_B][SPITCH];  // 33 KB
  int tid = threadIdx.x;
  int l = tid & 63, w = tid >> 6;
  int row16 = l & 15, half = l >> 4;
  long m0 = (long)blockIdx.x * TILE_B;
  float* out2 = out + (size_t)T_STEPS * B * 2;  // h0 passthrough output

  // ---------- phase 1: base'[32][512] = sc*(h0@W_hh^T + bc + spd*m2) ----------
  short8 afrag[2][4];
  #pragma unroll
  for (int mf = 0; mf < 2; mf++){
    #pragma unroll
    for (int kf = 0; kf < 4; kf++){
      long row = m0 + mf * 16 + row16;
      const f32x4* p = (const f32x4*)(h0 + row * H + kf * 32 + half * 8);
      f32x4 x = p[0], y = p[1];
      if (kf == w){                              // h0 copy, distributed over waves
        f32x4* q = (f32x4*)(out2 + row * H + kf * 32 + half * 8);
        q[0] = x; q[1] = y;
      }
      short8 a;
      #pragma unroll
      for (int i = 0; i < 4; i++){ a[i] = (short)f2bf(x[i]); a[4 + i] = (short)f2bf(y[i]); }
      afrag[mf][kf] = a;
    }
  }
  f32x4 acc[2][8];
  #pragma unroll
  for (int mf = 0; mf < 2; mf++)
    #pragma unroll
    for (int n = 0; n < 8; n++) acc[mf][n] = (f32x4){0.f, 0.f, 0.f, 0.f};

  // double-buffered W loads from the SHUFFLED layout (contiguous 1KB/wave/instr)
  short8 bfr[2][8];
  #pragma unroll
  for (int nfi = 0; nfi < 8; nfi++)
    bfr[0][nfi] = *(const short8*)(W_bf + (size_t)(((0 * 32 + w * 8 + nfi) * 64 + l)) * 8);
  #pragma unroll
  for (int kf = 0; kf < 4; kf++){
    if (kf < 3){
      #pragma unroll
      for (int nfi = 0; nfi < 8; nfi++)
        bfr[(kf + 1) & 1][nfi] =
          *(const short8*)(W_bf + (size_t)((((kf + 1) * 32 + w * 8 + nfi) * 64 + l)) * 8);
    }
    #pragma unroll
    for (int nfi = 0; nfi < 8; nfi++){
      acc[0][nfi] = __builtin_amdgcn_mfma_f32_16x16x32_bf16(afrag[0][kf], bfr[kf & 1][nfi], acc[0][nfi], 0, 0, 0);
      acc[1][nfi] = __builtin_amdgcn_mfma_f32_16x16x32_bf16(afrag[1][kf], bfr[kf & 1][nfi], acc[1][nfi], 0, 0, 0);
    }
  }
  // Epilogue: write into phase2-native layout.
  // j = qq*16 + row16 (qq = w*8+nfi) -> gate = qq>>3, k = (qq>>1)&3,
  // li2 = (qq&1)*16 + row16, pos = gate*GSTRIDE + li2*4 + k. Bijective over j.
  #pragma unroll
  for (int nfi = 0; nfi < 8; nfi++){
    int qq = w * 8 + nfi;
    int j = qq * 16 + row16;
    float bc = params[3 * FOURH + j];
    float m2 = params[2 * FOURH + j];
    float sc = ((qq >> 3) == 2) ? NEG_2LOG2E : NEG_LOG2E;
    int pos = (qq >> 3) * GSTRIDE + (((qq & 1) * 16 + row16) << 2) + ((qq >> 1) & 3);
    #pragma unroll
    for (int mf = 0; mf < 2; mf++){
      #pragma unroll
      for (int r = 0; r < 4; r++){
        int bl = mf * 16 + half * 4 + r;
        float v = sc * (acc[mf][nfi][r] + bc + spd[m0 + bl] * m2);
        sbase[bl][pos] = f2bf(v);
      }
    }
  }

  // ---- T14 issue-early: c0/lpr loads issued BEFORE the barrier so their HBM
  // latency folds into the barrier wait (acc/bfr dead here, low reg pressure).
  int li = (l & 15) | ((l >> 1) & 16);
  int grp = (l >> 4) & 1;
  float CD[4][4]; f32x2 RP[4];
  #pragma unroll
  for (int pp = 0; pp < 4; pp++){
    long b = m0 + w * 8 + pp * 2 + grp;
    #pragma unroll
    for (int k = 0; k < 4; k++) CD[pp][k] = c0[b * H + li + 32 * k];
    RP[pp] = ((const f32x2*)lpr)[b];
  }
  __syncthreads();

  // ---------- phase 2: ONE joint pass over 4 register-held pairs (8 b's/wave).
  float uu[4][4], vv[4][4], wp0[4], wp1[4];
  #pragma unroll
  for (int k = 0; k < 4; k++){
    int d = li + 32 * k;
    #pragma unroll
    for (int g = 0; g < 4; g++){
      uu[g][k] = params[g * H + d];
      vv[g][k] = params[FOURH + g * H + d];
    }
    wp0[k] = W_pos[d];
    wp1[k] = W_pos[H + d];
  }
  float bp0 = b_pos[0], bp1 = b_pos[1];

  float BB[4][4][4], R0[4], R1[4], SR0[4], SR1[4], PDX[4], PDY[4];
  int TL[4];
  #pragma unroll
  for (int pp = 0; pp < 4; pp++){
    int bl = w * 8 + pp * 2 + grp;
    #pragma unroll
    for (int g = 0; g < 4; g++){
      // one ds_read_b64: shorts {k=0,1,2,3} for this (gate, li)
      unsigned long long q =
        *(const unsigned long long*)&sbase[bl][g * GSTRIDE + (li << 2)];
      unsigned int u0 = (unsigned int)q, u1 = (unsigned int)(q >> 32);
      BB[pp][g][0] = __builtin_bit_cast(float, u0 << 16);
      BB[pp][g][1] = __builtin_bit_cast(float, u0 & 0xFFFF0000u);
      BB[pp][g][2] = __builtin_bit_cast(float, u1 << 16);
      BB[pp][g][3] = __builtin_bit_cast(float, u1 & 0xFFFF0000u);
    }
    R0[pp] = RP[pp][0]; R1[pp] = RP[pp][1];
    SR0[pp] = 0.f; SR1[pp] = 0.f;
    PDX[pp] = 0.f; PDY[pp] = 0.f;
    TL[pp] = T_STEPS - 1;
  }
  bool dn0 = false, dn1 = false, dn2 = false, dn3 = false;

#define STEP_PP(pp, dnf)                                                        \
  if (!dnf){                                                                    \
    float r0 = R0[pp], r1 = R1[pp];                                             \
    float gi[4], gf[4], gg[4], go[4];                                           \
    _Pragma("unroll")                                                           \
    for (int k = 0; k < 4; k++){                                                \
      gi[k] = fmaf(r1, vv[0][k], fmaf(r0, uu[0][k], BB[pp][0][k]));             \
      gf[k] = fmaf(r1, vv[1][k], fmaf(r0, uu[1][k], BB[pp][1][k]));             \
      gg[k] = fmaf(r1, vv[2][k], fmaf(r0, uu[2][k], BB[pp][2][k]));             \
      go[k] = fmaf(r1, vv[3][k], fmaf(r0, uu[3][k], BB[pp][3][k]));             \
    }                                                                           \
    float cn[4], so_[4];                                                        \
    _Pragma("unroll")                                                           \
    for (int k = 0; k < 4; k++){                                                \
      float Di = 1.0f + __builtin_amdgcn_exp2f(gi[k]);                          \
      float Df = 1.0f + __builtin_amdgcn_exp2f(gf[k]);                          \
      float Dg = 1.0f + __builtin_amdgcn_exp2f(gg[k]);                          \
      float Do = 1.0f + __builtin_amdgcn_exp2f(go[k]);                          \
      float si, sf, ig, so;                                                     \
      rcp4(Di, Df, Dg, Do, si, sf, ig, so);                                     \
      float tg = fmaf(2.0f, ig, -1.0f);                                         \
      cn[k] = fmaf(sf, CD[pp][k], si * tg);                                     \
      so_[k] = so;                                                              \
    }                                                                           \
    float Dc0 = 1.0f + __builtin_amdgcn_exp2f(NEG_2LOG2E * cn[0]);              \
    float Dc1 = 1.0f + __builtin_amdgcn_exp2f(NEG_2LOG2E * cn[1]);              \
    float Dc2 = 1.0f + __builtin_amdgcn_exp2f(NEG_2LOG2E * cn[2]);              \
    float Dc3 = 1.0f + __builtin_amdgcn_exp2f(NEG_2LOG2E * cn[3]);              \
    float ic0, ic1, ic2, ic3;                                                   \
    rcp4(Dc0, Dc1, Dc2, Dc3, ic0, ic1, ic2, ic3);                               \
    float hv0 = so_[0] * fmaf(2.0f, ic0, -1.0f);                                \
    float hv1 = so_[1] * fmaf(2.0f, ic1, -1.0f);                                \
    float hv2 = so_[2] * fmaf(2.0f, ic2, -1.0f);                                \
    float hv3 = so_[3] * fmaf(2.0f, ic3, -1.0f);                                \
    float a0 = fmaf(hv0, wp0[0], fmaf(hv1, wp0[1], fmaf(hv2, wp0[2], hv3 * wp0[3]))); \
    float a1 = fmaf(hv0, wp1[0], fmaf(hv1, wp1[1], fmaf(hv2, wp1[2], hv3 * wp1[3]))); \
    a0 = redb(a0);                                                              \
    a1 = redb(a1);                                                              \
    float n0 = a0 + bp0, n1 = a1 + bp1;                                         \
    float dx = n0 - r0, dy = n1 - r1;                                           \
    R0[pp] = n0; R1[pp] = n1;                                                   \
    SR0[pp] = (li == t) ? n0 : SR0[pp];                                         \
    SR1[pp] = (li == t) ? n1 : SR1[pp];                                         \
    int cf = (__builtin_fabsf(dx) < CONV_TOL) & (__builtin_fabsf(dy) < CONV_TOL); \
    if (__all(cf)){ dnf = true; TL[pp] = t; }                                   \
    else if (t >= 1){                                                           \
      float dcur2 = dx * dx + dy * dy;                                          \
      float dprev2 = PDX[pp] * PDX[pp] + PDY[pp] * PDY[pp];                     \
      float lam = (dx * PDX[pp] + dy * PDY[pp]) * __builtin_amdgcn_rcpf(dprev2); \
      float rsx = dx - lam * PDX[pp], rsy = dy - lam * PDY[pp];                 \
      float res2 = rsx * rsx + rsy * rsy;                                       \
      float f = lam * __builtin_amdgcn_rcpf(1.f - lam);                         \
      float esq = f * f * dcur2;                                                \
      int oks = (dprev2 > 1e-12f) & (res2 < 0.02f * dcur2) &                    \
                (__builtin_fabsf(lam) < 0.9f) &                                 \
                (esq < 2e-3f) & (dcur2 < 0.02f);                                \
      if (__all(oks)){                                                          \
        R0[pp] = fmaf(f, dx, n0);                                               \
        R1[pp] = fmaf(f, dy, n1);                                               \
        dnf = true; TL[pp] = t;   /* declare done at the jump */                \
      }                                                                         \
    }                                                                           \
    PDX[pp] = dx; PDY[pp] = dy;                                                 \
  }

  for (int t = 0; t < T_STEPS; t++){
    STEP_PP(0, dn0)
    STEP_PP(1, dn1)
    STEP_PP(2, dn2)
    STEP_PP(3, dn3)
    if (dn0 & dn1 & dn2 & dn3) break;
  }
#undef STEP_PP

  #pragma unroll
  for (int pp = 0; pp < 4; pp++){
    long b = m0 + w * 8 + pp * 2 + grp;
    float s0 = SR0[pp], s1 = SR1[pp];
    if (li > TL[pp]){ s0 = R0[pp]; s1 = R1[pp]; }
    f32x2 o; o[0] = s0; o[1] = s1;
    ((f32x2*)out)[(long)li * B + b] = o;
  }
}

extern "C" void kernel_launch(void* const* d_in, const int* in_sizes, int n_in,
                              void* d_out, int out_size, void* d_ws, size_t ws_size,
                              hipStream_t stream) {
  const float* lpr   = (const float*)d_in[1];   // last_pos_rel [B,2]
  const float* h0    = (const float*)d_in[2];   // [1,B,H]
  const float* c0    = (const float*)d_in[3];   // [1,B,H]
  const float* spd   = (const float*)d_in[4];   // last_speed_pos_rel [B,1]
  const float* W_ih  = (const float*)d_in[7];
  const float* W_hh  = (const float*)d_in[8];
  const float* b_ih  = (const float*)d_in[9];
  const float* b_hh  = (const float*)d_in[10];
  const float* W_emb = (const float*)d_in[11];
  const float* b_emb = (const float*)d_in[12];
  const float* W_pos = (const float*)d_in[13];
  const float* b_pos = (const float*)d_in[14];
  long B = in_sizes[0] / 2;                     // 65536
  float* out = (float*)d_out;

  // ws layout: params (8KB) | W_hh bf16 shuffled (128KB)
  float* params = (float*)d_ws;
  size_t pbytes = (size_t)4 * FOURH * sizeof(float);
  unsigned short* wbf = (unsigned short*)((char*)d_ws + pbytes);

  hipLaunchKernelGGL(k_prep, dim3(258), dim3(256), 0, stream,
                     W_hh, wbf, W_ih, b_ih, b_hh, W_emb, b_emb, params);
  hipLaunchKernelGGL(k_fused, dim3(B / TILE_B), dim3(256), 0, stream,
                     h0, wbf, spd, params, c0, lpr, W_pos, b_pos, out, B);
}